// Round 1
// baseline (2144.128 us; speedup 1.0000x reference)
//
#include <hip/hip_runtime.h>

#define HID 32

// ---- degree count: deg[dst] += 1 per edge ----
__global__ void k_deg_count(const int* __restrict__ dst, float* __restrict__ deg, int E) {
    int e = blockIdx.x * blockDim.x + threadIdx.x;
    if (e < E) atomicAdd(&deg[dst[e]], 1.0f);
}

// ---- dinv[i] = rsqrt(deg[i] + 1)  (the +1 is the self-loop) ----
__global__ void k_deg_to_dinv(float* __restrict__ deg, int N) {
    int i = blockIdx.x * blockDim.x + threadIdx.x;
    if (i < N) deg[i] = rsqrtf(deg[i] + 1.0f);
}

// ---- layer-1 linear + pre-scale: p[i][f] = (x[i][0]*W1[0][f] + x[i][1]*W1[1][f]) * dinv[i] ----
__global__ void k_lin1_scale(const float* __restrict__ x, const float* __restrict__ W1,
                             const float* __restrict__ dinv, float* __restrict__ p, int N) {
    int t = blockIdx.x * blockDim.x + threadIdx.x;
    int i = t >> 5, f = t & 31;
    if (i >= N) return;
    float v = x[2 * i] * W1[f] + x[2 * i + 1] * W1[HID + f];
    p[t] = v * dinv[i];
}

// ---- edge scatter: acc[dst] += p[src], 8 lanes per edge, float4 per lane ----
__global__ void k_scatter(const int* __restrict__ src, const int* __restrict__ dst,
                          const float* __restrict__ p, float* __restrict__ acc, long nthreads) {
    long t = (long)blockIdx.x * blockDim.x + threadIdx.x;
    if (t >= nthreads) return;
    int e = (int)(t >> 3);
    int q = (int)(t & 7);  // feature quad: 4q..4q+3
    int s = src[e], d = dst[e];
    const float4 v = *reinterpret_cast<const float4*>(&p[(long)s * HID + q * 4]);
    float* a = &acc[(long)d * HID + q * 4];
    atomicAdd(a + 0, v.x);
    atomicAdd(a + 1, v.y);
    atomicAdd(a + 2, v.z);
    atomicAdd(a + 3, v.w);
}

// ---- finalize layer (in-place on acc): acc = relu(dinv[i]*(acc + p) + b[f]) ----
__global__ void k_finalize_relu(const float* __restrict__ p, float* __restrict__ acc,
                                const float* __restrict__ b, const float* __restrict__ dinv, int N) {
    int t = blockIdx.x * blockDim.x + threadIdx.x;
    int i = t >> 5, f = t & 31;
    if (i >= N) return;
    acc[t] = fmaxf(dinv[i] * (acc[t] + p[t]) + b[f], 0.0f);
}

// ---- layer-2 linear + pre-scale: p[i][f] = (h1[i] @ W2)[f] * dinv[i], W2 staged in LDS ----
__global__ void k_lin2_scale(const float* __restrict__ h, const float* __restrict__ W2,
                             const float* __restrict__ dinv, float* __restrict__ p, int N) {
    __shared__ float Ws[HID * HID];
    for (int k = threadIdx.x; k < HID * HID; k += blockDim.x) Ws[k] = W2[k];
    __syncthreads();
    int t = blockIdx.x * blockDim.x + threadIdx.x;
    int i = t >> 5, f = t & 31;
    if (i >= N) return;
    const float* hr = &h[(long)i * HID];
    float s = 0.0f;
#pragma unroll
    for (int k = 0; k < HID; ++k) s += hr[k] * Ws[k * HID + f];
    p[t] = s * dinv[i];
}

// ---- finalize layer 2 + projection + sigmoid: out[i] = sigmoid(sum_f relu(...)*Wp[f] + bp) ----
__global__ void k_finalize_out(const float* __restrict__ p, const float* __restrict__ acc,
                               const float* __restrict__ b2, const float* __restrict__ Wp,
                               const float* __restrict__ bp, const float* __restrict__ dinv,
                               float* __restrict__ out, int N) {
    int i = blockIdx.x * blockDim.x + threadIdx.x;
    if (i >= N) return;
    float di = dinv[i];
    float s = 0.0f;
    const float* ar = &acc[(long)i * HID];
    const float* pr = &p[(long)i * HID];
#pragma unroll
    for (int f = 0; f < HID; ++f) {
        float hv = fmaxf(di * (ar[f] + pr[f]) + b2[f], 0.0f);
        s += hv * Wp[f];
    }
    s += bp[0];
    out[i] = 1.0f / (1.0f + expf(-s));
}

extern "C" void kernel_launch(void* const* d_in, const int* in_sizes, int n_in,
                              void* d_out, int out_size, void* d_ws, size_t ws_size,
                              hipStream_t stream) {
    const float* x  = (const float*)d_in[0];
    const int*   ei = (const int*)d_in[1];
    const float* W1 = (const float*)d_in[2];
    const float* b1 = (const float*)d_in[3];
    const float* W2 = (const float*)d_in[4];
    const float* b2 = (const float*)d_in[5];
    const float* Wp = (const float*)d_in[6];
    const float* bp = (const float*)d_in[7];
    float* out = (float*)d_out;

    const int N = in_sizes[0] / 2;   // IN_DIM = 2
    const int E = in_sizes[1] / 2;   // edge_index is [2, E]
    const int* src = ei;
    const int* dst = ei + E;

    // workspace layout: dinv [N], bufA [N*32], bufB [N*32]
    char* ws = (char*)d_ws;
    size_t off = 0;
    float* dinv = (float*)(ws + off);
    off += ((size_t)N * 4 + 255) & ~(size_t)255;
    float* bufA = (float*)(ws + off);
    off += ((size_t)N * HID * 4 + 255) & ~(size_t)255;
    float* bufB = (float*)(ws + off);

    const int BLK = 256;
    const long nfeat = (long)N * HID;
    const long nscat = (long)E * 8;

    // degrees -> dinv
    hipMemsetAsync(dinv, 0, (size_t)N * 4, stream);
    k_deg_count<<<(E + BLK - 1) / BLK, BLK, 0, stream>>>(dst, dinv, E);
    k_deg_to_dinv<<<(N + BLK - 1) / BLK, BLK, 0, stream>>>(dinv, N);

    // layer 1
    k_lin1_scale<<<(nfeat + BLK - 1) / BLK, BLK, 0, stream>>>(x, W1, dinv, bufA, N);
    hipMemsetAsync(bufB, 0, (size_t)N * HID * 4, stream);
    k_scatter<<<(nscat + BLK - 1) / BLK, BLK, 0, stream>>>(src, dst, bufA, bufB, nscat);
    k_finalize_relu<<<(nfeat + BLK - 1) / BLK, BLK, 0, stream>>>(bufA, bufB, b1, dinv, N);

    // layer 2 (h1 lives in bufB)
    k_lin2_scale<<<(nfeat + BLK - 1) / BLK, BLK, 0, stream>>>(bufB, W2, dinv, bufA, N);
    hipMemsetAsync(bufB, 0, (size_t)N * HID * 4, stream);
    k_scatter<<<(nscat + BLK - 1) / BLK, BLK, 0, stream>>>(src, dst, bufA, bufB, nscat);

    // finalize layer 2 + projection + sigmoid
    k_finalize_out<<<(N + BLK - 1) / BLK, BLK, 0, stream>>>(bufA, bufB, b2, Wp, bp, dinv, out, N);
}

// Round 4
// 563.270 us; speedup vs baseline: 3.8066x; 3.8066x over previous
//
#include <hip/hip_runtime.h>

#define HID 32

// ================= CSR construction =================

// histogram of in-degrees (int atomics into L2-resident 600KB array)
__global__ void k_hist(const int* __restrict__ dst, int* __restrict__ cnt, int E) {
    int e = blockIdx.x * blockDim.x + threadIdx.x;
    if (e < E) atomicAdd(&cnt[dst[e]], 1);
}

// dinv[i] = rsqrt(cnt[i] + 1)  (+1 = self-loop)
__global__ void k_dinv(const int* __restrict__ cnt, float* __restrict__ dinv, int N) {
    int i = blockIdx.x * blockDim.x + threadIdx.x;
    if (i < N) dinv[i] = rsqrtf((float)cnt[i] + 1.0f);
}

// per-block exclusive scan of cnt -> rowptr; block totals -> bsum
__global__ void k_scan1(const int* __restrict__ cnt, int* __restrict__ rowptr,
                        int* __restrict__ bsum, int N) {
    __shared__ int tmp[256];
    int tid = threadIdx.x;
    int i = blockIdx.x * 256 + tid;
    int v = (i < N) ? cnt[i] : 0;
    tmp[tid] = v;
    __syncthreads();
    for (int o = 1; o < 256; o <<= 1) {
        int t = (tid >= o) ? tmp[tid - o] : 0;
        __syncthreads();
        tmp[tid] += t;
        __syncthreads();
    }
    if (i < N) rowptr[i] = tmp[tid] - v;          // exclusive within block
    if (tid == 255) bsum[blockIdx.x] = tmp[255];  // block total
}

// exclusive scan of block sums (single block, NB <= 1024)
__global__ void k_scan2(int* __restrict__ bsum, int NB) {
    __shared__ int tmp[1024];
    int tid = threadIdx.x;
    int v = (tid < NB) ? bsum[tid] : 0;
    tmp[tid] = v;
    __syncthreads();
    for (int o = 1; o < 1024; o <<= 1) {
        int t = (tid >= o) ? tmp[tid - o] : 0;
        __syncthreads();
        tmp[tid] += t;
        __syncthreads();
    }
    if (tid < NB) bsum[tid] = tmp[tid] - v;
}

// add scanned block offsets; write rowptr[N]
__global__ void k_scan3(int* __restrict__ rowptr, const int* __restrict__ bsum,
                        const int* __restrict__ cnt, int N) {
    int i = blockIdx.x * 256 + threadIdx.x;
    if (i < N) {
        int r = rowptr[i] + bsum[blockIdx.x];
        rowptr[i] = r;
        if (i == N - 1) rowptr[N] = r + cnt[i];
    }
}

// scatter edges into CSR slots
__global__ void k_fill(const int* __restrict__ src, const int* __restrict__ dst,
                       const int* __restrict__ rowptr, int* __restrict__ cursor,
                       int* __restrict__ col, int E) {
    int e = blockIdx.x * blockDim.x + threadIdx.x;
    if (e < E) {
        int d = dst[e];
        int pos = atomicAdd(&cursor[d], 1);
        col[rowptr[d] + pos] = src[e];
    }
}

// ================= GCN compute =================

// layer-1 linear + pre-scale: p[i][f] = (x[i][0]*W1[0][f] + x[i][1]*W1[1][f]) * dinv[i]
__global__ void k_lin1_scale(const float* __restrict__ x, const float* __restrict__ W1,
                             const float* __restrict__ dinv, float* __restrict__ p, int N) {
    int t = blockIdx.x * blockDim.x + threadIdx.x;
    int i = t >> 5, f = t & 31;
    if (i >= N) return;
    float v = x[2 * i] * W1[f] + x[2 * i + 1] * W1[HID + f];
    p[t] = v * dinv[i];
}

// gather-aggregate + finalize + relu: h[d][f] = relu(dinv[d]*(sum_j p[col[j]][f] + p[d][f]) + b[f])
__global__ void k_gather_relu(const int* __restrict__ rowptr, const int* __restrict__ col,
                              const float* __restrict__ p, const float* __restrict__ b,
                              const float* __restrict__ dinv, float* __restrict__ h, int N) {
    int node = blockIdx.x * (blockDim.x >> 5) + (threadIdx.x >> 5);
    if (node >= N) return;
    int f = threadIdx.x & 31;
    int beg = rowptr[node], end = rowptr[node + 1];
    float s = p[(long)node * HID + f];  // self-loop term (pre-scaled)
    for (int j = beg; j < end; ++j) s += p[(long)col[j] * HID + f];
    h[(long)node * HID + f] = fmaxf(dinv[node] * s + b[f], 0.0f);
}

// layer-2 linear + pre-scale: p[i][f] = (h[i] @ W2)[f] * dinv[i], W2 in LDS
__global__ void k_lin2_scale(const float* __restrict__ h, const float* __restrict__ W2,
                             const float* __restrict__ dinv, float* __restrict__ p, int N) {
    __shared__ float Ws[HID * HID];
    for (int k = threadIdx.x; k < HID * HID; k += blockDim.x) Ws[k] = W2[k];
    __syncthreads();
    int t = blockIdx.x * blockDim.x + threadIdx.x;
    int i = t >> 5, f = t & 31;
    if (i >= N) return;
    const float* hr = &h[(long)i * HID];
    float s = 0.0f;
#pragma unroll
    for (int k = 0; k < HID; ++k) s += hr[k] * Ws[k * HID + f];
    p[t] = s * dinv[i];
}

// gather-aggregate + finalize + relu + projection + sigmoid, fused to [N,1] output
__global__ void k_gather_out(const int* __restrict__ rowptr, const int* __restrict__ col,
                             const float* __restrict__ p, const float* __restrict__ b2,
                             const float* __restrict__ Wp, const float* __restrict__ bp,
                             const float* __restrict__ dinv, float* __restrict__ out, int N) {
    int node = blockIdx.x * (blockDim.x >> 5) + (threadIdx.x >> 5);
    if (node >= N) return;
    int f = threadIdx.x & 31;
    int beg = rowptr[node], end = rowptr[node + 1];
    float s = p[(long)node * HID + f];
    for (int j = beg; j < end; ++j) s += p[(long)col[j] * HID + f];
    float hv = fmaxf(dinv[node] * s + b2[f], 0.0f);
    float v = hv * Wp[f];
#pragma unroll
    for (int m = 16; m > 0; m >>= 1) v += __shfl_xor(v, m, 32);
    if (f == 0) out[node] = 1.0f / (1.0f + expf(-(v + bp[0])));
}

extern "C" void kernel_launch(void* const* d_in, const int* in_sizes, int n_in,
                              void* d_out, int out_size, void* d_ws, size_t ws_size,
                              hipStream_t stream) {
    const float* x  = (const float*)d_in[0];
    const int*   ei = (const int*)d_in[1];
    const float* W1 = (const float*)d_in[2];
    const float* b1 = (const float*)d_in[3];
    const float* W2 = (const float*)d_in[4];
    const float* b2 = (const float*)d_in[5];
    const float* Wp = (const float*)d_in[6];
    const float* bp = (const float*)d_in[7];
    float* out = (float*)d_out;

    const int N = in_sizes[0] / 2;   // IN_DIM = 2
    const int E = in_sizes[1] / 2;   // edge_index is [2, E]
    const int* src = ei;
    const int* dst = ei + E;

    // ---- workspace layout (256B aligned) ----
    char* ws = (char*)d_ws;
    size_t off = 0;
    auto alloc = [&](size_t bytes) {
        void* ptr = ws + off;
        off += (bytes + 255) & ~(size_t)255;
        return ptr;
    };
    int*   cnt    = (int*)alloc((size_t)N * 4);
    int*   rowptr = (int*)alloc((size_t)(N + 1) * 4);
    int*   cursor = (int*)alloc((size_t)N * 4);
    int*   col    = (int*)alloc((size_t)E * 4);
    int*   bsum   = (int*)alloc(1024 * 4);
    float* dinv   = (float*)alloc((size_t)N * 4);
    float* bufA   = (float*)alloc((size_t)N * HID * 4);
    float* bufB   = (float*)alloc((size_t)N * HID * 4);

    const int BLK = 256;
    const int nb_e = (E + BLK - 1) / BLK;
    const int nb_n = (N + BLK - 1) / BLK;       // also = #scan blocks (<=1024 needed)
    const long nfeat = (long)N * HID;
    const int nb_f = (int)((nfeat + BLK - 1) / BLK);
    const int nodes_per_blk = BLK / 32;
    const int nb_g = (N + nodes_per_blk - 1) / nodes_per_blk;

    // ---- CSR build ----
    hipMemsetAsync(cnt, 0, (size_t)N * 4, stream);
    hipMemsetAsync(cursor, 0, (size_t)N * 4, stream);
    k_hist<<<nb_e, BLK, 0, stream>>>(dst, cnt, E);
    k_dinv<<<nb_n, BLK, 0, stream>>>(cnt, dinv, N);
    k_scan1<<<nb_n, BLK, 0, stream>>>(cnt, rowptr, bsum, N);
    k_scan2<<<1, 1024, 0, stream>>>(bsum, nb_n);
    k_scan3<<<nb_n, BLK, 0, stream>>>(rowptr, bsum, cnt, N);
    k_fill<<<nb_e, BLK, 0, stream>>>(src, dst, rowptr, cursor, col, E);

    // ---- layer 1 ----
    k_lin1_scale<<<nb_f, BLK, 0, stream>>>(x, W1, dinv, bufA, N);
    k_gather_relu<<<nb_g, BLK, 0, stream>>>(rowptr, col, bufA, b1, dinv, bufB, N);

    // ---- layer 2 + output head (fused) ----
    k_lin2_scale<<<nb_f, BLK, 0, stream>>>(bufB, W2, dinv, bufA, N);
    k_gather_out<<<nb_g, BLK, 0, stream>>>(rowptr, col, bufA, b2, Wp, bp, dinv, out, N);
}